// Round 1
// baseline (2775.505 us; speedup 1.0000x reference)
//
#include <hip/hip_runtime.h>
#include <hip/hip_bf16.h>
#include <math.h>

#define BB 128
#define DIMZ 512
#define NEXP 16
#define NCLS 1000

// ---------------- K1: conv1+relu+conv2+relu+pool2 fused ----------------
// grid (8,8,128), block 256. out p1 [128][32][64][64]
__global__ __launch_bounds__(256) void k_conv12(
    const float* __restrict__ x,
    const float* __restrict__ c1w, const float* __restrict__ c1b,
    const float* __restrict__ c2w, const float* __restrict__ c2b,
    float* __restrict__ p1)
{
    __shared__ float xs[3 * 20 * 20];     // x tile, origin (oy0-2, ox0-2)
    __shared__ float as1[32 * 324];       // conv1 act tile 18x18, origin (oy0-1, ox0-1)
    const int t = threadIdx.x;
    const int bx = blockIdx.x, by = blockIdx.y, b = blockIdx.z;
    const int ox0 = bx * 16, oy0 = by * 16;

    for (int idx = t; idx < 1200; idx += 256) {
        int c = idx / 400, rem = idx % 400, yy = rem / 20, xx = rem % 20;
        int gy = oy0 - 2 + yy, gx = ox0 - 2 + xx;
        float v = 0.f;
        if (gy >= 0 && gy < 128 && gx >= 0 && gx < 128)
            v = x[((b * 3 + c) * 128 + gy) * 128 + gx];
        xs[idx] = v;
    }
    __syncthreads();

    // conv1 into as1
    for (int p = t; p < 324; p += 256) {
        int ay = p / 18, ax = p % 18;
        int gy = oy0 - 1 + ay, gx = ox0 - 1 + ax;
        bool inimg = (gy >= 0 && gy < 128 && gx >= 0 && gx < 128);
        float acc[32];
        #pragma unroll
        for (int oc = 0; oc < 32; ++oc) acc[oc] = c1b[oc];
        for (int c = 0; c < 3; ++c) {
            float patch[9];
            #pragma unroll
            for (int ky = 0; ky < 3; ++ky)
                #pragma unroll
                for (int kx = 0; kx < 3; ++kx)
                    patch[ky * 3 + kx] = xs[c * 400 + (ay + ky) * 20 + (ax + kx)];
            #pragma unroll
            for (int oc = 0; oc < 32; ++oc) {
                const float* wp = c1w + (oc * 3 + c) * 9;
                float s = acc[oc];
                #pragma unroll
                for (int q = 0; q < 9; ++q) s += patch[q] * wp[q];
                acc[oc] = s;
            }
        }
        #pragma unroll
        for (int oc = 0; oc < 32; ++oc) {
            float v = acc[oc];
            v = v > 0.f ? v : 0.f;
            as1[oc * 324 + p] = inimg ? v : 0.f;
        }
    }
    __syncthreads();

    // conv2 at 16x16 positions, relu, 2x2 pool via shuffles
    {
        const int py = t >> 4, px = t & 15;
        float acc[32];
        #pragma unroll
        for (int oc = 0; oc < 32; ++oc) acc[oc] = c2b[oc];
        for (int ic = 0; ic < 32; ++ic) {
            float patch[9];
            #pragma unroll
            for (int ky = 0; ky < 3; ++ky)
                #pragma unroll
                for (int kx = 0; kx < 3; ++kx)
                    patch[ky * 3 + kx] = as1[ic * 324 + (py + ky) * 18 + (px + kx)];
            #pragma unroll
            for (int oc = 0; oc < 32; ++oc) {
                const float* wp = c2w + (oc * 32 + ic) * 9;
                float s = acc[oc];
                #pragma unroll
                for (int q = 0; q < 9; ++q) s += patch[q] * wp[q];
                acc[oc] = s;
            }
        }
        const bool act = ((px & 1) == 0) && ((py & 1) == 0);
        const int pox = (ox0 >> 1) + (px >> 1), poy = (oy0 >> 1) + (py >> 1);
        #pragma unroll
        for (int oc = 0; oc < 32; ++oc) {
            float v = acc[oc];
            v = v > 0.f ? v : 0.f;
            v += __shfl_xor(v, 1);
            v += __shfl_xor(v, 16);
            if (act) p1[((b * 32 + oc) * 64 + poy) * 64 + pox] = v * 0.25f;
        }
    }
}

// ---------------- K2: conv3+relu+pool2 ----------------
// grid (4,4,128), block 256. in p1 [128][32][64][64], out p2 [128][64][32][32]
__global__ __launch_bounds__(256) void k_conv3(
    const float* __restrict__ p1,
    const float* __restrict__ w, const float* __restrict__ bias,
    float* __restrict__ p2)
{
    __shared__ float s[32 * 324];
    const int t = threadIdx.x;
    const int bx = blockIdx.x, by = blockIdx.y, b = blockIdx.z;
    const int ox0 = bx * 16, oy0 = by * 16;

    for (int idx = t; idx < 32 * 324; idx += 256) {
        int ic = idx / 324, p = idx % 324, yy = p / 18, xx = p % 18;
        int gy = oy0 - 1 + yy, gx = ox0 - 1 + xx;
        float v = 0.f;
        if (gy >= 0 && gy < 64 && gx >= 0 && gx < 64)
            v = p1[((b * 32 + ic) * 64 + gy) * 64 + gx];
        s[idx] = v;
    }
    __syncthreads();

    const int py = t >> 4, px = t & 15;
    float acc[64];
    #pragma unroll
    for (int oc = 0; oc < 64; ++oc) acc[oc] = bias[oc];
    for (int ic = 0; ic < 32; ++ic) {
        float patch[9];
        #pragma unroll
        for (int ky = 0; ky < 3; ++ky)
            #pragma unroll
            for (int kx = 0; kx < 3; ++kx)
                patch[ky * 3 + kx] = s[ic * 324 + (py + ky) * 18 + (px + kx)];
        #pragma unroll
        for (int oc = 0; oc < 64; ++oc) {
            const float* wp = w + (oc * 32 + ic) * 9;
            float a = acc[oc];
            #pragma unroll
            for (int q = 0; q < 9; ++q) a += patch[q] * wp[q];
            acc[oc] = a;
        }
    }
    const bool act = ((px & 1) == 0) && ((py & 1) == 0);
    const int pox = (ox0 >> 1) + (px >> 1), poy = (oy0 >> 1) + (py >> 1);
    #pragma unroll
    for (int oc = 0; oc < 64; ++oc) {
        float v = acc[oc];
        v = v > 0.f ? v : 0.f;
        v += __shfl_xor(v, 1);
        v += __shfl_xor(v, 16);
        if (act) p2[((b * 64 + oc) * 32 + poy) * 32 + pox] = v * 0.25f;
    }
}

// ---------------- K3: conv4+relu+global mean ----------------
// grid (2,2,128), block 256. in p2 [128][64][32][32], out meanacc [128][64] (pre-zeroed)
__global__ __launch_bounds__(256) void k_conv4(
    const float* __restrict__ p2,
    const float* __restrict__ w, const float* __restrict__ bias,
    float* __restrict__ meanacc)
{
    __shared__ float s[32 * 324];
    const int t = threadIdx.x;
    const int bx = blockIdx.x, by = blockIdx.y, b = blockIdx.z;
    const int ox0 = bx * 16, oy0 = by * 16;
    const int py = t >> 4, px = t & 15;

    float acc[64];
    #pragma unroll
    for (int oc = 0; oc < 64; ++oc) acc[oc] = bias[oc];

    for (int half = 0; half < 2; ++half) {
        if (half) __syncthreads();
        for (int idx = t; idx < 32 * 324; idx += 256) {
            int icl = idx / 324, p = idx % 324, yy = p / 18, xx = p % 18;
            int gy = oy0 - 1 + yy, gx = ox0 - 1 + xx;
            float v = 0.f;
            if (gy >= 0 && gy < 32 && gx >= 0 && gx < 32)
                v = p2[((b * 64 + half * 32 + icl) * 32 + gy) * 32 + gx];
            s[idx] = v;
        }
        __syncthreads();
        for (int icl = 0; icl < 32; ++icl) {
            const int ic = half * 32 + icl;
            float patch[9];
            #pragma unroll
            for (int ky = 0; ky < 3; ++ky)
                #pragma unroll
                for (int kx = 0; kx < 3; ++kx)
                    patch[ky * 3 + kx] = s[icl * 324 + (py + ky) * 18 + (px + kx)];
            #pragma unroll
            for (int oc = 0; oc < 64; ++oc) {
                const float* wp = w + (oc * 64 + ic) * 9;
                float a = acc[oc];
                #pragma unroll
                for (int q = 0; q < 9; ++q) a += patch[q] * wp[q];
                acc[oc] = a;
            }
        }
    }

    #pragma unroll
    for (int oc = 0; oc < 64; ++oc) {
        float v = acc[oc];
        v = v > 0.f ? v : 0.f;
        v += __shfl_xor(v, 1);
        v += __shfl_xor(v, 2);
        v += __shfl_xor(v, 4);
        v += __shfl_xor(v, 8);
        v += __shfl_xor(v, 16);
        v += __shfl_xor(v, 32);
        if ((t & 63) == 0)
            atomicAdd(&meanacc[b * 64 + oc], v * (1.0f / 1024.0f));
    }
}

// ---------------- K4: proj + router + softmax + argmax + counts/importance ----------------
// grid 128, block 256. tail = d_out + 128000: [0]=aux, [1..16]=counts, [17..32]=importance
__global__ __launch_bounds__(256) void k_router(
    const float* __restrict__ meanacc,
    const float* __restrict__ pw, const float* __restrict__ pb,
    const float* __restrict__ rw, const float* __restrict__ rb,
    float* __restrict__ z, int* __restrict__ top1, float* __restrict__ tail)
{
    __shared__ float m[64];
    __shared__ float zs[512];
    __shared__ float part[256];
    __shared__ float gate[16];
    const int b = blockIdx.x, t = threadIdx.x;
    if (t < 64) m[t] = meanacc[b * 64 + t];
    __syncthreads();

    #pragma unroll
    for (int j = 0; j < 2; ++j) {
        int d = t + j * 256;
        float s = pb[d];
        for (int c = 0; c < 64; ++c) s += m[c] * pw[c * 512 + d];
        zs[d] = s;
        z[b * 512 + d] = s;
    }
    __syncthreads();
    {
        int e = t & 15, g = t >> 4;
        float s = 0.f;
        for (int j = 0; j < 32; ++j) {
            int d = g * 32 + j;
            s += zs[d] * rw[d * 16 + e];
        }
        part[t] = s;
    }
    __syncthreads();
    if (t < 16) {
        float s = rb[t];
        for (int g = 0; g < 16; ++g) s += part[g * 16 + t];
        gate[t] = s;
    }
    __syncthreads();
    if (t == 0) {
        float mx = gate[0];
        int am = 0;
        for (int e = 1; e < 16; ++e)
            if (gate[e] > mx) { mx = gate[e]; am = e; }
        float pr[16];
        float sum = 0.f;
        for (int e = 0; e < 16; ++e) { pr[e] = expf(gate[e] - mx); sum += pr[e]; }
        float inv = 1.f / sum;
        top1[b] = am;
        atomicAdd(&tail[1 + am], 1.0f / 128.0f);
        for (int e = 0; e < 16; ++e)
            atomicAdd(&tail[17 + e], pr[e] * inv * (1.0f / 128.0f));
    }
}

// ---------------- K5: aux loss ----------------
__global__ void k_aux(float* __restrict__ tail)
{
    if (threadIdx.x == 0) {
        float s = 0.f;
        for (int e = 0; e < 16; ++e) s += tail[1 + e] * tail[17 + e];
        tail[0] = 16.0f * s;
    }
}

// ---------------- K6: expert layer 1 ----------------
// grid 128, block 256
__global__ __launch_bounds__(256) void k_exp1(
    const float* __restrict__ z, const int* __restrict__ top1,
    const float* __restrict__ w1, const float* __restrict__ b1,
    float* __restrict__ h1)
{
    __shared__ float zs[512];
    const int b = blockIdx.x, t = threadIdx.x;
    const int e = top1[b];
    zs[t] = z[b * 512 + t];
    zs[t + 256] = z[b * 512 + 256 + t];
    __syncthreads();
    const float* W = w1 + (size_t)e * 512 * 512;
    #pragma unroll
    for (int j = 0; j < 2; ++j) {
        int k = t + j * 256;
        float s = b1[e * 512 + k];
        for (int d = 0; d < 512; ++d) s += zs[d] * W[d * 512 + k];
        h1[b * 512 + k] = s > 0.f ? s : 0.f;
    }
}

// ---------------- K7: expert layer 2 ----------------
// grid 128, block 256
__global__ __launch_bounds__(256) void k_exp2(
    const float* __restrict__ h1, const int* __restrict__ top1,
    const float* __restrict__ w2, const float* __restrict__ b2,
    float* __restrict__ out)
{
    __shared__ float hs[512];
    const int b = blockIdx.x, t = threadIdx.x;
    const int e = top1[b];
    hs[t] = h1[b * 512 + t];
    hs[t + 256] = h1[b * 512 + 256 + t];
    __syncthreads();
    const float* W = w2 + (size_t)e * 512 * 1000;
    #pragma unroll
    for (int j = 0; j < 4; ++j) {
        int n = t + j * 256;
        if (n < 1000) {
            float s = b2[e * 1000 + n];
            for (int d = 0; d < 512; ++d) s += hs[d] * W[d * 1000 + n];
            out[b * 1000 + n] = s;
        }
    }
}

extern "C" void kernel_launch(void* const* d_in, const int* in_sizes, int n_in,
                              void* d_out, int out_size, void* d_ws, size_t ws_size,
                              hipStream_t stream)
{
    const float* x   = (const float*)d_in[0];
    const float* c1w = (const float*)d_in[1];
    const float* c1b = (const float*)d_in[2];
    const float* c2w = (const float*)d_in[3];
    const float* c2b = (const float*)d_in[4];
    const float* c3w = (const float*)d_in[5];
    const float* c3b = (const float*)d_in[6];
    const float* c4w = (const float*)d_in[7];
    const float* c4b = (const float*)d_in[8];
    const float* pw  = (const float*)d_in[9];
    const float* pb  = (const float*)d_in[10];
    const float* rw  = (const float*)d_in[11];
    const float* rb  = (const float*)d_in[12];
    const float* w1  = (const float*)d_in[13];
    const float* b1  = (const float*)d_in[14];
    const float* w2  = (const float*)d_in[15];
    const float* b2  = (const float*)d_in[16];

    float* out = (float*)d_out;
    float* tail = out + 128000;   // aux, counts[16], importance[16]

    // ws layout (floats)
    float* ws = (float*)d_ws;
    float* p1      = ws;                       // 128*32*64*64 = 16777216
    float* p2      = p1 + 16777216;            // 128*64*32*32 = 8388608
    float* meanacc = p2 + 8388608;             // 8192
    float* z       = meanacc + 8192;           // 65536
    float* h1      = z + 65536;                // 65536
    int*   top1    = (int*)(h1 + 65536);       // 128

    hipMemsetAsync(meanacc, 0, 8192 * sizeof(float), stream);
    hipMemsetAsync(tail, 0, 33 * sizeof(float), stream);

    k_conv12<<<dim3(8, 8, 128), 256, 0, stream>>>(x, c1w, c1b, c2w, c2b, p1);
    k_conv3 <<<dim3(4, 4, 128), 256, 0, stream>>>(p1, c3w, c3b, p2);
    k_conv4 <<<dim3(2, 2, 128), 256, 0, stream>>>(p2, c4w, c4b, meanacc);
    k_router<<<128, 256, 0, stream>>>(meanacc, pw, pb, rw, rb, z, top1, tail);
    k_aux   <<<1, 64, 0, stream>>>(tail);
    k_exp1  <<<128, 256, 0, stream>>>(z, top1, w1, b1, h1);
    k_exp2  <<<128, 256, 0, stream>>>(h1, top1, w2, b2, out);
}

// Round 2
// 322.746 us; speedup vs baseline: 8.5997x; 8.5997x over previous
//
#include <hip/hip_runtime.h>
#include <math.h>

typedef unsigned short ushort_t;
typedef short short8 __attribute__((ext_vector_type(8)));
typedef float f32x16 __attribute__((ext_vector_type(16)));

#define MFMA32(A,B,C) __builtin_amdgcn_mfma_f32_32x32x16_bf16(A,B,C,0,0,0)

__device__ __forceinline__ ushort_t f2bf(float f) {
    union { float f; unsigned u; } c; c.f = f;
    unsigned u = c.u;
    unsigned r = (u + 0x7FFFu + ((u >> 16) & 1u)) >> 16;
    return (ushort_t)r;
}

// ---------- weight repack: f32 OIHW -> bf16 MFMA-frag rows ----------
// row r (8064 rows): value(lane,j) laid out so a lane's 8 k-values are one dwordx4.
// kappa(g,j) = g*8+j  (consistent for A and B frags -> k-permutation invariant)
__global__ __launch_bounds__(256) void k_wcvt(
    const float* __restrict__ c2w, const float* __restrict__ c3w, const float* __restrict__ c4w,
    ushort_t* __restrict__ w2f, ushort_t* __restrict__ w3f, ushort_t* __restrict__ w4f)
{
    int r = blockIdx.x * 256 + threadIdx.x;
    if (r >= 8064) return;
    int lane = r & 63, m = lane & 31, g = (lane >> 5) & 1;
    if (r < 1152) {                       // conv2: f = tau*2+h, 18 frags
        int f = r >> 6, tau = f >> 1, h = f & 1, ky = tau / 3, kx = tau % 3;
        #pragma unroll
        for (int j = 0; j < 8; ++j) {
            int ic = h * 16 + g * 8 + j;
            w2f[r * 8 + j] = f2bf(c2w[((m * 32 + ic) * 3 + ky) * 3 + kx]);
        }
    } else if (r < 3456) {                // conv3: f = ot*18 + tau*2 + h, 36 frags
        int rr = r - 1152;
        int f = rr >> 6;
        int ot = f / 18, fl = f % 18, tau = fl >> 1, h = fl & 1, ky = tau / 3, kx = tau % 3;
        int oc = ot * 32 + m;
        #pragma unroll
        for (int j = 0; j < 8; ++j) {
            int ic = h * 16 + g * 8 + j;
            w3f[rr * 8 + j] = f2bf(c3w[((oc * 32 + ic) * 3 + ky) * 3 + kx]);
        }
    } else {                              // conv4: f = ot*36 + tau*4 + h, 72 frags
        int rr = r - 3456;
        int f = rr >> 6;
        int ot = f / 36, fl = f % 36, tau = fl >> 2, h = fl & 3, ky = tau / 3, kx = tau % 3;
        int oc = ot * 32 + m;
        #pragma unroll
        for (int j = 0; j < 8; ++j) {
            int ic = h * 16 + g * 8 + j;
            w4f[rr * 8 + j] = f2bf(c4w[((oc * 64 + ic) * 3 + ky) * 3 + kx]);
        }
    }
}

// ---------- K_A: conv1 (VALU) + conv2 (MFMA) + relu + pool -> a2 bf16 NHWC [128][64][64][32]
// grid (8,16,128): tile = 16 cols x 8 rows of conv2 output. 4 waves, wave w -> rows 2w,2w+1.
__global__ __launch_bounds__(256) void k_c12(
    const float* __restrict__ x,
    const float* __restrict__ c1w, const float* __restrict__ c1b,
    const ushort_t* __restrict__ w2f, const float* __restrict__ c2b,
    ushort_t* __restrict__ a2)
{
    __shared__ float xs[3][12][20];
    __shared__ __align__(16) ushort_t a1s[180 * 40];   // 10x18 cells, 32 ic + 8 pad
    __shared__ float c2bs[32];
    const int t = threadIdx.x;
    const int bx = blockIdx.x, by = blockIdx.y, b = blockIdx.z;
    const int ox0 = bx * 16, oy0 = by * 8;

    if (t < 32) c2bs[t] = c2b[t];
    for (int idx = t; idx < 720; idx += 256) {
        int c = idx / 240, rem = idx % 240, yy = rem / 20, xx = rem % 20;
        int gy = oy0 - 2 + yy, gx = ox0 - 2 + xx;
        float v = 0.f;
        if (gy >= 0 && gy < 128 && gx >= 0 && gx < 128)
            v = x[((b * 3 + c) * 128 + gy) * 128 + gx];
        xs[c][yy][xx] = v;
    }
    __syncthreads();

    // conv1 for the 10x18 halo region
    if (t < 180) {
        int cy = t / 18, cx = t % 18;
        int gy = oy0 - 1 + cy, gx = ox0 - 1 + cx;
        bool inimg = (gy >= 0 && gy < 128 && gx >= 0 && gx < 128);
        float acc[32];
        #pragma unroll
        for (int oc = 0; oc < 32; ++oc) acc[oc] = c1b[oc];
        #pragma unroll
        for (int c = 0; c < 3; ++c) {
            float patch[9];
            #pragma unroll
            for (int ky = 0; ky < 3; ++ky)
                #pragma unroll
                for (int kx = 0; kx < 3; ++kx)
                    patch[ky * 3 + kx] = xs[c][cy + ky][cx + kx];
            #pragma unroll
            for (int oc = 0; oc < 32; ++oc) {
                const float* wp = c1w + (oc * 3 + c) * 9;
                float sv = acc[oc];
                #pragma unroll
                for (int q = 0; q < 9; ++q) sv += patch[q] * wp[q];
                acc[oc] = sv;
            }
        }
        ushort_t* dst = &a1s[(cy * 18 + cx) * 40];
        #pragma unroll
        for (int qq = 0; qq < 4; ++qq) {
            short8 v8;
            #pragma unroll
            for (int j = 0; j < 8; ++j) {
                float vv = acc[qq * 8 + j];
                vv = vv > 0.f ? vv : 0.f;
                v8[j] = inimg ? (short)f2bf(vv) : (short)0;
            }
            *(short8*)(dst + qq * 8) = v8;
        }
    }
    __syncthreads();

    // conv2 via MFMA: A = weights (m=oc), B = im2col acts (n=position)
    const int wave = t >> 6, lane = t & 63;
    const int n = lane & 31, g = lane >> 5;
    const int ry = n >> 4, rx = n & 15;
    const int y2 = wave * 2 + ry;

    short8 af[18];
    #pragma unroll
    for (int f = 0; f < 18; ++f)
        af[f] = *(const short8*)(w2f + (f * 64 + lane) * 8);

    f32x16 acc;
    #pragma unroll
    for (int i = 0; i < 16; ++i) acc[i] = 0.f;

    #pragma unroll
    for (int tau = 0; tau < 9; ++tau) {
        int dy = tau / 3, dx = tau % 3;
        const ushort_t* base = &a1s[((y2 + dy) * 18 + (rx + dx)) * 40 + g * 8];
        short8 b0 = *(const short8*)(base);
        short8 b1 = *(const short8*)(base + 16);
        acc = MFMA32(af[tau * 2 + 0], b0, acc);
        acc = MFMA32(af[tau * 2 + 1], b1, acc);
    }

    const int opy = by * 4 + wave;
    const int opx = bx * 8 + (rx >> 1);
    #pragma unroll
    for (int r = 0; r < 16; ++r) {
        int oc = (r & 3) + 8 * (r >> 2) + 4 * g;
        float v = acc[r] + c2bs[oc];
        v = v > 0.f ? v : 0.f;
        v += __shfl_xor(v, 1);
        v += __shfl_xor(v, 16);
        if ((lane & 17) == 0)
            a2[(((size_t)b * 64 + opy) * 64 + opx) * 32 + oc] = f2bf(v * 0.25f);
    }
}

// ---------- K_B: conv3 (MFMA) + relu + pool -> a3 bf16 NHWC [128][32][32][64]
// grid (4,16,128): tile 16 cols x 4 rows. wave: ot = w&1 (oc half), rg = w>>1 (row pair).
__global__ __launch_bounds__(256) void k_c3(
    const ushort_t* __restrict__ a2, const ushort_t* __restrict__ w3f,
    const float* __restrict__ c3b, ushort_t* __restrict__ a3)
{
    __shared__ __align__(16) ushort_t s[108 * 40];   // 6x18 cells
    __shared__ float bs[64];
    const int t = threadIdx.x;
    const int bx = blockIdx.x, by = blockIdx.y, b = blockIdx.z;
    const int x0 = bx * 16, y0 = by * 4;
    if (t < 64) bs[t] = c3b[t];
    for (int idx = t; idx < 432; idx += 256) {
        int cell = idx >> 2, part = idx & 3;
        int cy = cell / 18, cx = cell % 18;
        int gy = y0 - 1 + cy, gx = x0 - 1 + cx;
        uint4 v = make_uint4(0, 0, 0, 0);
        if (gy >= 0 && gy < 64 && gx >= 0 && gx < 64)
            v = *(const uint4*)(a2 + (((size_t)b * 64 + gy) * 64 + gx) * 32 + part * 8);
        *(uint4*)(&s[cell * 40 + part * 8]) = v;
    }
    __syncthreads();

    const int wave = t >> 6, lane = t & 63;
    const int ot = wave & 1, rg = wave >> 1;
    const int n = lane & 31, g = lane >> 5;
    const int ry = n >> 4, rx = n & 15;
    const int y3 = rg * 2 + ry;

    short8 af[18];
    #pragma unroll
    for (int f = 0; f < 18; ++f)
        af[f] = *(const short8*)(w3f + (((ot * 18 + f) * 64) + lane) * 8);

    f32x16 acc;
    #pragma unroll
    for (int i = 0; i < 16; ++i) acc[i] = 0.f;

    #pragma unroll
    for (int tau = 0; tau < 9; ++tau) {
        int dy = tau / 3, dx = tau % 3;
        const ushort_t* base = &s[((y3 + dy) * 18 + (rx + dx)) * 40 + g * 8];
        short8 b0 = *(const short8*)(base);
        short8 b1 = *(const short8*)(base + 16);
        acc = MFMA32(af[tau * 2 + 0], b0, acc);
        acc = MFMA32(af[tau * 2 + 1], b1, acc);
    }

    const int opy = by * 2 + rg;
    const int opx = bx * 8 + (rx >> 1);
    #pragma unroll
    for (int r = 0; r < 16; ++r) {
        int oc = (r & 3) + 8 * (r >> 2) + 4 * g;
        float v = acc[r] + bs[ot * 32 + oc];
        v = v > 0.f ? v : 0.f;
        v += __shfl_xor(v, 1);
        v += __shfl_xor(v, 16);
        if ((lane & 17) == 0)
            a3[(((size_t)b * 32 + opy) * 32 + opx) * 64 + ot * 32 + oc] = f2bf(v * 0.25f);
    }
}

// ---------- K_C: conv4 (MFMA) + relu + global mean -> feat f32 [128][64]
// grid (2,8,128): tile 16 cols x 4 rows. wave: ot = w&1, rg = w>>1.
__global__ __launch_bounds__(256) void k_c4(
    const ushort_t* __restrict__ a3, const ushort_t* __restrict__ w4f,
    const float* __restrict__ c4b, float* __restrict__ feat)
{
    __shared__ __align__(16) ushort_t s[108 * 72];   // 6x18 cells, 64 ic + 8 pad
    __shared__ float bs[64];
    const int t = threadIdx.x;
    const int bx = blockIdx.x, by = blockIdx.y, b = blockIdx.z;
    const int x0 = bx * 16, y0 = by * 4;
    if (t < 64) bs[t] = c4b[t];
    for (int idx = t; idx < 864; idx += 256) {
        int cell = idx >> 3, part = idx & 7;
        int cy = cell / 18, cx = cell % 18;
        int gy = y0 - 1 + cy, gx = x0 - 1 + cx;
        uint4 v = make_uint4(0, 0, 0, 0);
        if (gy >= 0 && gy < 32 && gx >= 0 && gx < 32)
            v = *(const uint4*)(a3 + (((size_t)b * 32 + gy) * 32 + gx) * 64 + part * 8);
        *(uint4*)(&s[cell * 72 + part * 8]) = v;
    }
    __syncthreads();

    const int wave = t >> 6, lane = t & 63;
    const int ot = wave & 1, rg = wave >> 1;
    const int n = lane & 31, g = lane >> 5;
    const int ry = n >> 4, rx = n & 15;
    const int y4 = rg * 2 + ry;

    f32x16 acc;
    #pragma unroll
    for (int i = 0; i < 16; ++i) acc[i] = 0.f;

    #pragma unroll
    for (int hp = 0; hp < 2; ++hp) {            // ic half-pairs: h = hp*2 + u
        short8 af[18];
        #pragma unroll
        for (int tau = 0; tau < 9; ++tau)
            #pragma unroll
            for (int u = 0; u < 2; ++u)
                af[tau * 2 + u] = *(const short8*)(w4f + (((ot * 36 + tau * 4 + hp * 2 + u) * 64) + lane) * 8);
        #pragma unroll
        for (int tau = 0; tau < 9; ++tau) {
            int dy = tau / 3, dx = tau % 3;
            const ushort_t* base = &s[((y4 + dy) * 18 + (rx + dx)) * 72 + hp * 32 + g * 8];
            short8 b0 = *(const short8*)(base);
            short8 b1 = *(const short8*)(base + 16);
            acc = MFMA32(af[tau * 2 + 0], b0, acc);
            acc = MFMA32(af[tau * 2 + 1], b1, acc);
        }
    }

    #pragma unroll
    for (int r = 0; r < 16; ++r) {
        int oc = (r & 3) + 8 * (r >> 2) + 4 * g;
        float v = acc[r] + bs[ot * 32 + oc];
        v = v > 0.f ? v : 0.f;
        v += __shfl_xor(v, 1);
        v += __shfl_xor(v, 2);
        v += __shfl_xor(v, 4);
        v += __shfl_xor(v, 8);
        v += __shfl_xor(v, 16);
        if ((lane & 31) == 0)
            atomicAdd(&feat[b * 64 + ot * 32 + oc], v * (1.0f / 1024.0f));
    }
}

// ---------- router ----------
__global__ __launch_bounds__(256) void k_router(
    const float* __restrict__ meanacc,
    const float* __restrict__ pw, const float* __restrict__ pb,
    const float* __restrict__ rw, const float* __restrict__ rb,
    float* __restrict__ z, int* __restrict__ top1, float* __restrict__ tail)
{
    __shared__ float m[64];
    __shared__ float zs[512];
    __shared__ float part[256];
    __shared__ float gate[16];
    const int b = blockIdx.x, t = threadIdx.x;
    if (t < 64) m[t] = meanacc[b * 64 + t];
    __syncthreads();

    #pragma unroll
    for (int j = 0; j < 2; ++j) {
        int d = t + j * 256;
        float s = pb[d];
        for (int c = 0; c < 64; ++c) s += m[c] * pw[c * 512 + d];
        zs[d] = s;
        z[b * 512 + d] = s;
    }
    __syncthreads();
    {
        int e = t & 15, gg = t >> 4;
        float s = 0.f;
        for (int j = 0; j < 32; ++j) {
            int d = gg * 32 + j;
            s += zs[d] * rw[d * 16 + e];
        }
        part[t] = s;
    }
    __syncthreads();
    if (t < 16) {
        float s = rb[t];
        for (int gg = 0; gg < 16; ++gg) s += part[gg * 16 + t];
        gate[t] = s;
    }
    __syncthreads();
    if (t == 0) {
        float mx = gate[0];
        int am = 0;
        for (int e = 1; e < 16; ++e)
            if (gate[e] > mx) { mx = gate[e]; am = e; }
        float pr[16];
        float sum = 0.f;
        for (int e = 0; e < 16; ++e) { pr[e] = expf(gate[e] - mx); sum += pr[e]; }
        float inv = 1.f / sum;
        top1[b] = am;
        atomicAdd(&tail[1 + am], 1.0f / 128.0f);
        for (int e = 0; e < 16; ++e)
            atomicAdd(&tail[17 + e], pr[e] * inv * (1.0f / 128.0f));
    }
}

__global__ void k_aux(float* __restrict__ tail)
{
    if (threadIdx.x == 0) {
        float s = 0.f;
        for (int e = 0; e < 16; ++e) s += tail[1 + e] * tail[17 + e];
        tail[0] = 16.0f * s;
    }
}

// ---------- experts ----------
__global__ __launch_bounds__(256) void k_exp1(
    const float* __restrict__ z, const int* __restrict__ top1,
    const float* __restrict__ w1, const float* __restrict__ b1,
    float* __restrict__ h1)
{
    __shared__ float zs[512];
    const int bid = blockIdx.x;
    const int b = bid >> 1, half = bid & 1, t = threadIdx.x;
    const int e = top1[b];
    zs[t] = z[b * 512 + t];
    zs[t + 256] = z[b * 512 + 256 + t];
    __syncthreads();
    const float* W = w1 + (size_t)e * 262144;
    int k = half * 256 + t;
    float s = b1[e * 512 + k];
    for (int d = 0; d < 512; ++d) s += zs[d] * W[d * 512 + k];
    h1[b * 512 + k] = s > 0.f ? s : 0.f;
}

__global__ __launch_bounds__(256) void k_exp2(
    const float* __restrict__ h1, const int* __restrict__ top1,
    const float* __restrict__ w2, const float* __restrict__ b2,
    float* __restrict__ out)
{
    __shared__ float hs[512];
    const int bid = blockIdx.x;
    const int b = bid >> 2, q = bid & 3, t = threadIdx.x;
    const int e = top1[b];
    hs[t] = h1[b * 512 + t];
    hs[t + 256] = h1[b * 512 + 256 + t];
    __syncthreads();
    const float* W = w2 + (size_t)e * 512000;
    if (t < 250) {
        int nn = q * 250 + t;
        float s = b2[e * 1000 + nn];
        for (int d = 0; d < 512; ++d) s += hs[d] * W[d * 1000 + nn];
        out[b * 1000 + nn] = s;
    }
}

extern "C" void kernel_launch(void* const* d_in, const int* in_sizes, int n_in,
                              void* d_out, int out_size, void* d_ws, size_t ws_size,
                              hipStream_t stream)
{
    const float* x   = (const float*)d_in[0];
    const float* c1w = (const float*)d_in[1];
    const float* c1b = (const float*)d_in[2];
    const float* c2w = (const float*)d_in[3];
    const float* c2b = (const float*)d_in[4];
    const float* c3w = (const float*)d_in[5];
    const float* c3b = (const float*)d_in[6];
    const float* c4w = (const float*)d_in[7];
    const float* c4b = (const float*)d_in[8];
    const float* pw  = (const float*)d_in[9];
    const float* pb  = (const float*)d_in[10];
    const float* rw  = (const float*)d_in[11];
    const float* rb  = (const float*)d_in[12];
    const float* w1  = (const float*)d_in[13];
    const float* b1  = (const float*)d_in[14];
    const float* w2  = (const float*)d_in[15];
    const float* b2  = (const float*)d_in[16];

    float* out = (float*)d_out;
    float* tail = out + 128000;   // aux, counts[16], importance[16]

    // ws layout (bytes)
    char* w = (char*)d_ws;
    ushort_t* a2  = (ushort_t*)(w);                  // 33554432 B
    ushort_t* a3  = (ushort_t*)(w + 33554432);       // 16777216 B
    ushort_t* w2f = (ushort_t*)(w + 50331648);       // 18432 B
    ushort_t* w3f = (ushort_t*)(w + 50350080);       // 36864 B
    ushort_t* w4f = (ushort_t*)(w + 50386944);       // 73728 B
    float*    feat= (float*)(w + 50460672);          // 32768 B
    float*    z   = (float*)(w + 50493440);          // 262144 B
    float*    h1  = (float*)(w + 50755584);          // 262144 B
    int*      top1= (int*)(w + 51017728);            // 512 B

    hipMemsetAsync(feat, 0, 8192 * sizeof(float), stream);
    hipMemsetAsync(tail, 0, 33 * sizeof(float), stream);

    k_wcvt  <<<32, 256, 0, stream>>>(c2w, c3w, c4w, w2f, w3f, w4f);
    k_c12   <<<dim3(8, 16, 128), 256, 0, stream>>>(x, c1w, c1b, w2f, c2b, a2);
    k_c3    <<<dim3(4, 16, 128), 256, 0, stream>>>(a2, w3f, c3b, a3);
    k_c4    <<<dim3(2, 8, 128), 256, 0, stream>>>(a3, w4f, c4b, feat);
    k_router<<<128, 256, 0, stream>>>(feat, pw, pb, rw, rb, z, top1, tail);
    k_aux   <<<1, 64, 0, stream>>>(tail);
    k_exp1  <<<256, 256, 0, stream>>>(z, top1, w1, b1, h1);
    k_exp2  <<<512, 256, 0, stream>>>(h1, top1, w2, b2, out);
}